// Round 1
// baseline (655.590 us; speedup 1.0000x reference)
//
#include <hip/hip_runtime.h>
#include <math.h>

#define N_NODES 100000
#define N_EDGES 1600000
#define D 128
#define NEG_SLOPE_F 0.2f

// ---------------- GEMM: h = x @ W^T ----------------
// x:[N,128], W:[128,128] row-major; h[r][c] = sum_k x[r][k]*W[c][k]
// block: 256 threads (ty=16 x tx=16), tile 64 rows x 128 cols, thread tile 4x8
__global__ __launch_bounds__(256) void gemm_h(const float* __restrict__ x,
                                              const float* __restrict__ W,
                                              float* __restrict__ h, int n) {
    __shared__ float Xs[64][132];
    __shared__ float Ws[128][132];
    int tid = threadIdx.x;
    int tx = tid & 15, ty = tid >> 4;
    int row0 = blockIdx.x * 64;

    // stage W: 128x128 floats = 4096 float4, 16 per thread
    const float4* W4 = (const float4*)W;
    for (int i = 0; i < 16; ++i) {
        int idx = tid + i * 256;
        int r = idx >> 5;
        int c4 = idx & 31;
        float4 v = W4[r * 32 + c4];
        *(float4*)&Ws[r][c4 * 4] = v;
    }
    // stage X tile: 64 rows x 128 = 2048 float4, 8 per thread
    const float4* X4 = (const float4*)x;
    for (int i = 0; i < 8; ++i) {
        int idx = tid + i * 256;
        int r = idx >> 5;
        int c4 = idx & 31;
        int gr = row0 + r;
        float4 v = (gr < n) ? X4[(size_t)gr * 32 + c4] : make_float4(0.f, 0.f, 0.f, 0.f);
        *(float4*)&Xs[r][c4 * 4] = v;
    }
    __syncthreads();

    float acc[4][8];
#pragma unroll
    for (int i = 0; i < 4; ++i)
#pragma unroll
        for (int j = 0; j < 8; ++j) acc[i][j] = 0.f;

    for (int k4 = 0; k4 < 32; ++k4) {
        float4 xf[4], wf[8];
#pragma unroll
        for (int i = 0; i < 4; ++i) xf[i] = *(const float4*)&Xs[ty + 16 * i][k4 * 4];
#pragma unroll
        for (int j = 0; j < 8; ++j) wf[j] = *(const float4*)&Ws[tx + 16 * j][k4 * 4];
#pragma unroll
        for (int i = 0; i < 4; ++i)
#pragma unroll
            for (int j = 0; j < 8; ++j) {
                acc[i][j] += xf[i].x * wf[j].x + xf[i].y * wf[j].y +
                             xf[i].z * wf[j].z + xf[i].w * wf[j].w;
            }
    }

#pragma unroll
    for (int i = 0; i < 4; ++i) {
        int gr = row0 + ty + 16 * i;
        if (gr < n) {
#pragma unroll
            for (int j = 0; j < 8; ++j)
                h[(size_t)gr * 128 + tx + 16 * j] = acc[i][j];
        }
    }
}

// ---------------- e_l / e_r: per-row dots with a_left / a_right ----------------
__global__ __launch_bounds__(256) void el_er(const float* __restrict__ h,
                                             const float* __restrict__ a_l,
                                             const float* __restrict__ a_r,
                                             float* __restrict__ e_l,
                                             float* __restrict__ e_r, int n) {
    int wid = threadIdx.x >> 6;
    int lane = threadIdx.x & 63;
    int r = blockIdx.x * 4 + wid;
    if (r >= n) return;
    float2 hv = *(const float2*)&h[(size_t)r * 128 + lane * 2];
    float2 al = *(const float2*)&a_l[lane * 2];
    float2 ar = *(const float2*)&a_r[lane * 2];
    float sl = hv.x * al.x + hv.y * al.y;
    float sr = hv.x * ar.x + hv.y * ar.y;
#pragma unroll
    for (int o = 32; o; o >>= 1) {
        sl += __shfl_xor(sl, o);
        sr += __shfl_xor(sr, o);
    }
    if (lane == 0) { e_l[r] = sl; e_r[r] = sr; }
}

// ---------------- degree histogram ----------------
__global__ void hist(const int* __restrict__ dst, int* __restrict__ deg) {
    int i = blockIdx.x * blockDim.x + threadIdx.x;
    if (i < N_EDGES) atomicAdd(&deg[dst[i]], 1);
}

// ---------------- single-block exclusive scan -> row_ptr, cursor ----------------
__global__ __launch_bounds__(1024) void scan_deg(const int* __restrict__ deg,
                                                 int* __restrict__ row_ptr,
                                                 int* __restrict__ cursor) {
    __shared__ int part[1024];
    int tid = threadIdx.x;
    const int chunk = (N_NODES + 1023) / 1024;  // 98
    int start = tid * chunk;
    int end = min(start + chunk, N_NODES);
    int s = 0;
    for (int i = start; i < end; ++i) s += deg[i];
    part[tid] = s;
    __syncthreads();
    for (int off = 1; off < 1024; off <<= 1) {
        int v = (tid >= off) ? part[tid - off] : 0;
        __syncthreads();
        part[tid] += v;
        __syncthreads();
    }
    int run = (tid == 0) ? 0 : part[tid - 1];
    for (int i = start; i < end; ++i) {
        row_ptr[i] = run;
        cursor[i] = run;
        run += deg[i];
    }
    if (tid == 1023) row_ptr[N_NODES] = part[1023];
}

// ---------------- scatter edges into CSR order by dst ----------------
__global__ void scatter(const int* __restrict__ src, const int* __restrict__ dst,
                        int* __restrict__ cursor, int* __restrict__ src_sorted) {
    int i = blockIdx.x * blockDim.x + threadIdx.x;
    if (i < N_EDGES) {
        int p = atomicAdd(&cursor[dst[i]], 1);
        src_sorted[p] = src[i];
    }
}

// ---------------- per-node softmax + weighted aggregation (1 wave / node) ------
__global__ __launch_bounds__(256) void node_aggregate(
        const float* __restrict__ h, const float* __restrict__ e_l,
        const float* __restrict__ e_r, const int* __restrict__ row_ptr,
        const int* __restrict__ src_sorted, float* __restrict__ out) {
    int wid = threadIdx.x >> 6, lane = threadIdx.x & 63;
    int d = blockIdx.x * 4 + wid;
    if (d >= N_NODES) return;
    int start = row_ptr[d], end = row_ptr[d + 1];
    float erd = e_r[d];

    // pass 1: segment max of leaky-relu logits
    float m = -INFINITY;
    for (int base = start; base < end; base += 64) {
        int k = base + lane;
        if (k < end) {
            float e = e_l[src_sorted[k]] + erd;
            e = (e >= 0.f) ? e : NEG_SLOPE_F * e;
            m = fmaxf(m, e);
        }
    }
#pragma unroll
    for (int o = 32; o; o >>= 1) m = fmaxf(m, __shfl_xor(m, o));

    // pass 2: exp + weighted accumulation of h rows
    float denom = 0.f;
    float accx = 0.f, accy = 0.f;
    for (int base = start; base < end; base += 64) {
        int k = base + lane;
        int cnt = min(64, end - base);
        int s = 0;
        float ex = 0.f;
        if (k < end) {
            s = src_sorted[k];
            float e = e_l[s] + erd;
            e = (e >= 0.f) ? e : NEG_SLOPE_F * e;
            ex = __expf(e - m);
        }
        denom += ex;
        for (int j = 0; j < cnt; ++j) {
            float exj = __shfl(ex, j);
            int sj = __shfl(s, j);
            float2 hv = *(const float2*)&h[(size_t)sj * 128 + lane * 2];
            accx += exj * hv.x;
            accy += exj * hv.y;
        }
    }
#pragma unroll
    for (int o = 32; o; o >>= 1) denom += __shfl_xor(denom, o);
    float inv = 1.f / fmaxf(denom, 1e-38f);
    float2 o2 = make_float2(accx * inv, accy * inv);
    *(float2*)&out[(size_t)d * 128 + lane * 2] = o2;
}

extern "C" void kernel_launch(void* const* d_in, const int* in_sizes, int n_in,
                              void* d_out, int out_size, void* d_ws, size_t ws_size,
                              hipStream_t stream) {
    const float* x   = (const float*)d_in[0];
    const int*   src = (const int*)d_in[1];
    const int*   dst = (const int*)d_in[2];
    const float* W   = (const float*)d_in[3];
    const float* a_l = (const float*)d_in[4];
    const float* a_r = (const float*)d_in[5];
    float* out = (float*)d_out;

    char* ws = (char*)d_ws;
    float* h         = (float*)ws; ws += (size_t)N_NODES * D * 4;
    float* e_l       = (float*)ws; ws += (size_t)N_NODES * 4;
    float* e_r       = (float*)ws; ws += (size_t)N_NODES * 4;
    int*   deg       = (int*)ws;   ws += (size_t)N_NODES * 4;
    int*   row_ptr   = (int*)ws;   ws += (size_t)(N_NODES + 1) * 4;
    int*   cursor    = (int*)ws;   ws += (size_t)N_NODES * 4;
    int*   src_sorted= (int*)ws;   ws += (size_t)N_EDGES * 4;

    hipMemsetAsync(deg, 0, (size_t)N_NODES * 4, stream);

    gemm_h<<<(N_NODES + 63) / 64, 256, 0, stream>>>(x, W, h, N_NODES);
    el_er<<<(N_NODES + 3) / 4, 256, 0, stream>>>(h, a_l, a_r, e_l, e_r, N_NODES);
    hist<<<(N_EDGES + 255) / 256, 256, 0, stream>>>(dst, deg);
    scan_deg<<<1, 1024, 0, stream>>>(deg, row_ptr, cursor);
    scatter<<<(N_EDGES + 255) / 256, 256, 0, stream>>>(src, dst, cursor, src_sorted);
    node_aggregate<<<(N_NODES + 3) / 4, 256, 0, stream>>>(h, e_l, e_r, row_ptr, src_sorted, out);
}

// Round 2
// 431.287 us; speedup vs baseline: 1.5201x; 1.5201x over previous
//
#include <hip/hip_runtime.h>
#include <math.h>

#define N_NODES 100000
#define N_EDGES 1600000
#define D 128
#define NEG_SLOPE_F 0.2f
#define NSB 98  // ceil(N_NODES / 1024) scan blocks

// ---------------- GEMM: h = x @ W^T, fused e_l/e_r epilogue ----------------
// x:[N,128], W:[128,128] row-major; h[r][c] = sum_k x[r][k]*W[c][k]
// block: 256 threads (ty=16 x tx=16), tile 64 rows x 128 cols, thread tile 4x8
__global__ __launch_bounds__(256) void gemm_h(const float* __restrict__ x,
                                              const float* __restrict__ W,
                                              const float* __restrict__ a_l,
                                              const float* __restrict__ a_r,
                                              float* __restrict__ h,
                                              float* __restrict__ e_l,
                                              float* __restrict__ e_r, int n) {
    __shared__ float Xs[64][132];
    __shared__ float Ws[128][132];
    int tid = threadIdx.x;
    int tx = tid & 15, ty = tid >> 4;
    int row0 = blockIdx.x * 64;

    // stage W: 128x128 floats = 4096 float4, 16 per thread
    const float4* W4 = (const float4*)W;
    for (int i = 0; i < 16; ++i) {
        int idx = tid + i * 256;
        int r = idx >> 5;
        int c4 = idx & 31;
        float4 v = W4[r * 32 + c4];
        *(float4*)&Ws[r][c4 * 4] = v;
    }
    // stage X tile: 64 rows x 128 = 2048 float4, 8 per thread
    const float4* X4 = (const float4*)x;
    for (int i = 0; i < 8; ++i) {
        int idx = tid + i * 256;
        int r = idx >> 5;
        int c4 = idx & 31;
        int gr = row0 + r;
        float4 v = (gr < n) ? X4[(size_t)gr * 32 + c4] : make_float4(0.f, 0.f, 0.f, 0.f);
        *(float4*)&Xs[r][c4 * 4] = v;
    }
    __syncthreads();

    float acc[4][8];
#pragma unroll
    for (int i = 0; i < 4; ++i)
#pragma unroll
        for (int j = 0; j < 8; ++j) acc[i][j] = 0.f;

    for (int k4 = 0; k4 < 32; ++k4) {
        float4 xf[4], wf[8];
#pragma unroll
        for (int i = 0; i < 4; ++i) xf[i] = *(const float4*)&Xs[ty + 16 * i][k4 * 4];
#pragma unroll
        for (int j = 0; j < 8; ++j) wf[j] = *(const float4*)&Ws[tx + 16 * j][k4 * 4];
#pragma unroll
        for (int i = 0; i < 4; ++i)
#pragma unroll
            for (int j = 0; j < 8; ++j) {
                acc[i][j] += xf[i].x * wf[j].x + xf[i].y * wf[j].y +
                             xf[i].z * wf[j].z + xf[i].w * wf[j].w;
            }
    }

    // write h
#pragma unroll
    for (int i = 0; i < 4; ++i) {
        int gr = row0 + ty + 16 * i;
        if (gr < n) {
#pragma unroll
            for (int j = 0; j < 8; ++j)
                h[(size_t)gr * 128 + tx + 16 * j] = acc[i][j];
        }
    }

    // fused epilogue: e_l[r] = h[r]·a_l, e_r[r] = h[r]·a_r
    float pl[4] = {0.f, 0.f, 0.f, 0.f}, pr[4] = {0.f, 0.f, 0.f, 0.f};
#pragma unroll
    for (int j = 0; j < 8; ++j) {
        float alv = a_l[tx + 16 * j];
        float arv = a_r[tx + 16 * j];
#pragma unroll
        for (int i = 0; i < 4; ++i) {
            pl[i] += acc[i][j] * alv;
            pr[i] += acc[i][j] * arv;
        }
    }
#pragma unroll
    for (int o = 8; o; o >>= 1) {
#pragma unroll
        for (int i = 0; i < 4; ++i) {
            pl[i] += __shfl_xor(pl[i], o);
            pr[i] += __shfl_xor(pr[i], o);
        }
    }
    if (tx == 0) {
#pragma unroll
        for (int i = 0; i < 4; ++i) {
            int gr = row0 + ty + 16 * i;
            if (gr < n) { e_l[gr] = pl[i]; e_r[gr] = pr[i]; }
        }
    }
}

// ---------------- degree histogram ----------------
__global__ void hist(const int* __restrict__ dst, int* __restrict__ deg) {
    int i = blockIdx.x * blockDim.x + threadIdx.x;
    if (i < N_EDGES) atomicAdd(&deg[dst[i]], 1);
}

// ---------------- parallel scan, 3 kernels ----------------
// K1: per-block partial sums over 1024-element chunks
__global__ __launch_bounds__(256) void block_sums(const int* __restrict__ deg,
                                                  int* __restrict__ bsum) {
    int tid = threadIdx.x, lane = tid & 63, wid = tid >> 6;
    int base = blockIdx.x * 1024 + tid * 4;
    int s = 0;
#pragma unroll
    for (int k = 0; k < 4; ++k) {
        int i = base + k;
        if (i < N_NODES) s += deg[i];
    }
#pragma unroll
    for (int o = 32; o; o >>= 1) s += __shfl_xor(s, o);
    __shared__ int wt[4];
    if (lane == 0) wt[wid] = s;
    __syncthreads();
    if (tid == 0) bsum[blockIdx.x] = wt[0] + wt[1] + wt[2] + wt[3];
}

// K2: scan the 98 block sums (single tiny block), also write row_ptr[N_NODES]
__global__ __launch_bounds__(128) void scan_bsums(const int* __restrict__ bsum,
                                                  int* __restrict__ bofs,
                                                  int* __restrict__ row_ptr) {
    int tid = threadIdx.x, lane = tid & 63, wid = tid >> 6;
    int v = (tid < NSB) ? bsum[tid] : 0;
    int inc = v;
#pragma unroll
    for (int o = 1; o < 64; o <<= 1) {
        int nv = __shfl_up(inc, o);
        if (lane >= o) inc += nv;
    }
    __shared__ int wtot[2];
    if (lane == 63) wtot[wid] = inc;
    __syncthreads();
    int add = (wid == 1) ? wtot[0] : 0;
    int excl = inc - v + add;
    if (tid < NSB) bofs[tid] = excl;
    if (tid == NSB - 1) row_ptr[N_NODES] = excl + v;
}

// K3: each block scans its 1024-chunk, offset by bofs, emits row_ptr + cursor
__global__ __launch_bounds__(256) void emit_rowptr(const int* __restrict__ deg,
                                                   const int* __restrict__ bofs,
                                                   int* __restrict__ row_ptr,
                                                   int* __restrict__ cursor) {
    int tid = threadIdx.x, lane = tid & 63, wid = tid >> 6;
    int base = blockIdx.x * 1024 + tid * 4;
    int v[4];
    int s = 0;
#pragma unroll
    for (int k = 0; k < 4; ++k) {
        int i = base + k;
        v[k] = (i < N_NODES) ? deg[i] : 0;
        s += v[k];
    }
    int inc = s;
#pragma unroll
    for (int o = 1; o < 64; o <<= 1) {
        int nv = __shfl_up(inc, o);
        if (lane >= o) inc += nv;
    }
    __shared__ int wt[4];
    if (lane == 63) wt[wid] = inc;
    __syncthreads();
    int wofs = 0;
#pragma unroll
    for (int w = 0; w < 4; ++w)
        if (w < wid) wofs += wt[w];
    int excl = inc - s + wofs + bofs[blockIdx.x];
#pragma unroll
    for (int k = 0; k < 4; ++k) {
        int i = base + k;
        if (i < N_NODES) { row_ptr[i] = excl; cursor[i] = excl; }
        excl += v[k];
    }
}

// ---------------- scatter edges into CSR order by dst ----------------
__global__ void scatter(const int* __restrict__ src, const int* __restrict__ dst,
                        int* __restrict__ cursor, int* __restrict__ src_sorted) {
    int i = blockIdx.x * blockDim.x + threadIdx.x;
    if (i < N_EDGES) {
        int p = atomicAdd(&cursor[dst[i]], 1);
        src_sorted[p] = src[i];
    }
}

// ---------------- per-node softmax + weighted aggregation (1 wave / node) ------
__global__ __launch_bounds__(256) void node_aggregate(
        const float* __restrict__ h, const float* __restrict__ e_l,
        const float* __restrict__ e_r, const int* __restrict__ row_ptr,
        const int* __restrict__ src_sorted, float* __restrict__ out) {
    int wid = threadIdx.x >> 6, lane = threadIdx.x & 63;
    int d = blockIdx.x * 4 + wid;
    if (d >= N_NODES) return;
    int start = row_ptr[d], end = row_ptr[d + 1];
    float erd = e_r[d];

    // pass 1: segment max of leaky-relu logits
    float m = -INFINITY;
    for (int base = start; base < end; base += 64) {
        int k = base + lane;
        if (k < end) {
            float e = e_l[src_sorted[k]] + erd;
            e = (e >= 0.f) ? e : NEG_SLOPE_F * e;
            m = fmaxf(m, e);
        }
    }
#pragma unroll
    for (int o = 32; o; o >>= 1) m = fmaxf(m, __shfl_xor(m, o));

    // pass 2: exp + weighted accumulation of h rows
    float denom = 0.f;
    float accx = 0.f, accy = 0.f;
    for (int base = start; base < end; base += 64) {
        int k = base + lane;
        int cnt = min(64, end - base);
        int s = 0;
        float ex = 0.f;
        if (k < end) {
            s = src_sorted[k];
            float e = e_l[s] + erd;
            e = (e >= 0.f) ? e : NEG_SLOPE_F * e;
            ex = __expf(e - m);
        }
        denom += ex;
        for (int j = 0; j < cnt; ++j) {
            float exj = __shfl(ex, j);
            int sj = __shfl(s, j);
            float2 hv = *(const float2*)&h[(size_t)sj * 128 + lane * 2];
            accx += exj * hv.x;
            accy += exj * hv.y;
        }
    }
#pragma unroll
    for (int o = 32; o; o >>= 1) denom += __shfl_xor(denom, o);
    float inv = 1.f / fmaxf(denom, 1e-38f);
    float2 o2 = make_float2(accx * inv, accy * inv);
    *(float2*)&out[(size_t)d * 128 + lane * 2] = o2;
}

extern "C" void kernel_launch(void* const* d_in, const int* in_sizes, int n_in,
                              void* d_out, int out_size, void* d_ws, size_t ws_size,
                              hipStream_t stream) {
    const float* x   = (const float*)d_in[0];
    const int*   src = (const int*)d_in[1];
    const int*   dst = (const int*)d_in[2];
    const float* W   = (const float*)d_in[3];
    const float* a_l = (const float*)d_in[4];
    const float* a_r = (const float*)d_in[5];
    float* out = (float*)d_out;

    char* ws = (char*)d_ws;
    float* h         = (float*)ws; ws += (size_t)N_NODES * D * 4;
    float* e_l       = (float*)ws; ws += (size_t)N_NODES * 4;
    float* e_r       = (float*)ws; ws += (size_t)N_NODES * 4;
    int*   deg       = (int*)ws;   ws += (size_t)N_NODES * 4;
    int*   row_ptr   = (int*)ws;   ws += (size_t)(N_NODES + 1) * 4;
    int*   cursor    = (int*)ws;   ws += (size_t)N_NODES * 4;
    int*   src_sorted= (int*)ws;   ws += (size_t)N_EDGES * 4;
    int*   bsum      = (int*)ws;   ws += (size_t)NSB * 4;
    int*   bofs      = (int*)ws;   ws += (size_t)NSB * 4;

    hipMemsetAsync(deg, 0, (size_t)N_NODES * 4, stream);

    gemm_h<<<(N_NODES + 63) / 64, 256, 0, stream>>>(x, W, a_l, a_r, h, e_l, e_r, N_NODES);
    hist<<<(N_EDGES + 255) / 256, 256, 0, stream>>>(dst, deg);
    block_sums<<<NSB, 256, 0, stream>>>(deg, bsum);
    scan_bsums<<<1, 128, 0, stream>>>(bsum, bofs, row_ptr);
    emit_rowptr<<<NSB, 256, 0, stream>>>(deg, bofs, row_ptr, cursor);
    scatter<<<(N_EDGES + 255) / 256, 256, 0, stream>>>(src, dst, cursor, src_sorted);
    node_aggregate<<<(N_NODES + 3) / 4, 256, 0, stream>>>(h, e_l, e_r, row_ptr, src_sorted, out);
}

// Round 3
// 336.447 us; speedup vs baseline: 1.9486x; 1.2819x over previous
//
#include <hip/hip_runtime.h>
#include <math.h>

#define N_NODES 100000
#define N_EDGES 1600000
#define D 128
#define NEG_SLOPE_F 0.2f
#define NSB 98  // ceil(N_NODES / 1024) scan blocks

__device__ __forceinline__ unsigned short f2bf_rtn(float f) {
    unsigned int u = __float_as_uint(f);
    u += 0x7fffu + ((u >> 16) & 1u);  // round-to-nearest-even
    return (unsigned short)(u >> 16);
}

// ---------------- GEMM: h = x @ W^T (bf16 out), fused e_l/e_r epilogue --------
// Two K-phases of 64 so LDS = 52 KB -> 3 blocks/CU.
__global__ __launch_bounds__(256) void gemm_h(const float* __restrict__ x,
                                              const float* __restrict__ W,
                                              const float* __restrict__ a_l,
                                              const float* __restrict__ a_r,
                                              unsigned short* __restrict__ hb,
                                              float* __restrict__ e_l,
                                              float* __restrict__ e_r, int n) {
    __shared__ float Xs[64][68];
    __shared__ float Ws[128][68];
    int tid = threadIdx.x;
    int tx = tid & 15, ty = tid >> 4;
    int row0 = blockIdx.x * 64;

    float acc[4][8];
#pragma unroll
    for (int i = 0; i < 4; ++i)
#pragma unroll
        for (int j = 0; j < 8; ++j) acc[i][j] = 0.f;

    const float4* W4 = (const float4*)W;
    const float4* X4 = (const float4*)x;

    for (int ph = 0; ph < 2; ++ph) {
        // stage W k-half: 128 rows x 16 float4
        for (int i = 0; i < 8; ++i) {
            int idx = tid + i * 256;
            int r = idx >> 4;
            int c4 = idx & 15;
            float4 v = W4[r * 32 + ph * 16 + c4];
            *(float4*)&Ws[r][c4 * 4] = v;
        }
        // stage X k-half: 64 rows x 16 float4
        for (int i = 0; i < 4; ++i) {
            int idx = tid + i * 256;
            int r = idx >> 4;
            int c4 = idx & 15;
            int gr = row0 + r;
            float4 v = (gr < n) ? X4[(size_t)gr * 32 + ph * 16 + c4]
                                : make_float4(0.f, 0.f, 0.f, 0.f);
            *(float4*)&Xs[r][c4 * 4] = v;
        }
        __syncthreads();

        for (int k4 = 0; k4 < 16; ++k4) {
            float4 xf[4], wf[8];
#pragma unroll
            for (int i = 0; i < 4; ++i) xf[i] = *(const float4*)&Xs[ty + 16 * i][k4 * 4];
#pragma unroll
            for (int j = 0; j < 8; ++j) wf[j] = *(const float4*)&Ws[tx + 16 * j][k4 * 4];
#pragma unroll
            for (int i = 0; i < 4; ++i)
#pragma unroll
                for (int j = 0; j < 8; ++j) {
                    acc[i][j] += xf[i].x * wf[j].x + xf[i].y * wf[j].y +
                                 xf[i].z * wf[j].z + xf[i].w * wf[j].w;
                }
        }
        __syncthreads();
    }

    // write h (bf16)
#pragma unroll
    for (int i = 0; i < 4; ++i) {
        int gr = row0 + ty + 16 * i;
        if (gr < n) {
#pragma unroll
            for (int j = 0; j < 8; ++j)
                hb[(size_t)gr * 128 + tx + 16 * j] = f2bf_rtn(acc[i][j]);
        }
    }

    // fused epilogue: e_l[r] = h[r]·a_l, e_r[r] = h[r]·a_r (fp32 acc)
    float pl[4] = {0.f, 0.f, 0.f, 0.f}, pr[4] = {0.f, 0.f, 0.f, 0.f};
#pragma unroll
    for (int j = 0; j < 8; ++j) {
        float alv = a_l[tx + 16 * j];
        float arv = a_r[tx + 16 * j];
#pragma unroll
        for (int i = 0; i < 4; ++i) {
            pl[i] += acc[i][j] * alv;
            pr[i] += acc[i][j] * arv;
        }
    }
#pragma unroll
    for (int o = 8; o; o >>= 1) {
#pragma unroll
        for (int i = 0; i < 4; ++i) {
            pl[i] += __shfl_xor(pl[i], o);
            pr[i] += __shfl_xor(pr[i], o);
        }
    }
    if (tx == 0) {
#pragma unroll
        for (int i = 0; i < 4; ++i) {
            int gr = row0 + ty + 16 * i;
            if (gr < n) { e_l[gr] = pl[i]; e_r[gr] = pr[i]; }
        }
    }
}

// ---------------- degree histogram ----------------
__global__ void hist(const int* __restrict__ dst, int* __restrict__ deg) {
    int i = blockIdx.x * blockDim.x + threadIdx.x;
    if (i < N_EDGES) atomicAdd(&deg[dst[i]], 1);
}

// ---------------- parallel scan, 3 kernels ----------------
__global__ __launch_bounds__(256) void block_sums(const int* __restrict__ deg,
                                                  int* __restrict__ bsum) {
    int tid = threadIdx.x, lane = tid & 63, wid = tid >> 6;
    int base = blockIdx.x * 1024 + tid * 4;
    int s = 0;
#pragma unroll
    for (int k = 0; k < 4; ++k) {
        int i = base + k;
        if (i < N_NODES) s += deg[i];
    }
#pragma unroll
    for (int o = 32; o; o >>= 1) s += __shfl_xor(s, o);
    __shared__ int wt[4];
    if (lane == 0) wt[wid] = s;
    __syncthreads();
    if (tid == 0) bsum[blockIdx.x] = wt[0] + wt[1] + wt[2] + wt[3];
}

__global__ __launch_bounds__(128) void scan_bsums(const int* __restrict__ bsum,
                                                  int* __restrict__ bofs,
                                                  int* __restrict__ row_ptr) {
    int tid = threadIdx.x, lane = tid & 63, wid = tid >> 6;
    int v = (tid < NSB) ? bsum[tid] : 0;
    int inc = v;
#pragma unroll
    for (int o = 1; o < 64; o <<= 1) {
        int nv = __shfl_up(inc, o);
        if (lane >= o) inc += nv;
    }
    __shared__ int wtot[2];
    if (lane == 63) wtot[wid] = inc;
    __syncthreads();
    int add = (wid == 1) ? wtot[0] : 0;
    int excl = inc - v + add;
    if (tid < NSB) bofs[tid] = excl;
    if (tid == NSB - 1) row_ptr[N_NODES] = excl + v;
}

__global__ __launch_bounds__(256) void emit_rowptr(const int* __restrict__ deg,
                                                   const int* __restrict__ bofs,
                                                   int* __restrict__ row_ptr,
                                                   int* __restrict__ cursor) {
    int tid = threadIdx.x, lane = tid & 63, wid = tid >> 6;
    int base = blockIdx.x * 1024 + tid * 4;
    int v[4];
    int s = 0;
#pragma unroll
    for (int k = 0; k < 4; ++k) {
        int i = base + k;
        v[k] = (i < N_NODES) ? deg[i] : 0;
        s += v[k];
    }
    int inc = s;
#pragma unroll
    for (int o = 1; o < 64; o <<= 1) {
        int nv = __shfl_up(inc, o);
        if (lane >= o) inc += nv;
    }
    __shared__ int wt[4];
    if (lane == 63) wt[wid] = inc;
    __syncthreads();
    int wofs = 0;
#pragma unroll
    for (int w = 0; w < 4; ++w)
        if (w < wid) wofs += wt[w];
    int excl = inc - s + wofs + bofs[blockIdx.x];
#pragma unroll
    for (int k = 0; k < 4; ++k) {
        int i = base + k;
        if (i < N_NODES) { row_ptr[i] = excl; cursor[i] = excl; }
        excl += v[k];
    }
}

// ---------------- scatter edges into CSR order by dst ----------------
__global__ void scatter(const int* __restrict__ src, const int* __restrict__ dst,
                        int* __restrict__ cursor, int* __restrict__ src_sorted) {
    int i = blockIdx.x * blockDim.x + threadIdx.x;
    if (i < N_EDGES) {
        int p = atomicAdd(&cursor[dst[i]], 1);
        src_sorted[p] = src[i];
    }
}

// ---------------- per-node softmax + aggregation ----------------
// 1 wave/node. 16-lane group per edge (lane loads 16 B = 8 bf16 cols),
// 4 edges concurrent per wave, unrolled x4 -> up to 4 row-loads in flight/lane.
__global__ __launch_bounds__(256) void node_aggregate(
        const unsigned short* __restrict__ hb, const float* __restrict__ e_l,
        const float* __restrict__ e_r, const int* __restrict__ row_ptr,
        const int* __restrict__ src_sorted, float* __restrict__ out) {
    __shared__ int   lds_s[4][64];
    __shared__ float lds_e[4][64];
    int wid = threadIdx.x >> 6, lane = threadIdx.x & 63;
    int g = lane >> 4, p = lane & 15;
    int d = blockIdx.x * 4 + wid;
    if (d >= N_NODES) return;
    int start = row_ptr[d], end = row_ptr[d + 1];
    float erd = e_r[d];

    // pass 1: segment max of leaky-relu logits
    float m = -INFINITY;
    for (int base = start; base < end; base += 64) {
        int k = base + lane;
        if (k < end) {
            float e = e_l[src_sorted[k]] + erd;
            e = (e >= 0.f) ? e : NEG_SLOPE_F * e;
            m = fmaxf(m, e);
        }
    }
#pragma unroll
    for (int o = 32; o; o >>= 1) m = fmaxf(m, __shfl_xor(m, o));

    // pass 2: exp + weighted accumulation
    float denom = 0.f;
    float acc[8];
#pragma unroll
    for (int q = 0; q < 8; ++q) acc[q] = 0.f;

    for (int base = start; base < end; base += 64) {
        int k = base + lane;
        int valid = k < end;
        int s = valid ? src_sorted[k] : 0;
        float ex = 0.f;
        if (valid) {
            float e = e_l[s] + erd;
            e = (e >= 0.f) ? e : NEG_SLOPE_F * e;
            ex = __expf(e - m);
        }
        denom += ex;
        lds_s[wid][lane] = s;
        lds_e[wid][lane] = ex;
        asm volatile("s_waitcnt lgkmcnt(0)" ::: "memory");

        int cnt = min(64, end - base);
        int nst = (cnt + 3) >> 2;
        int u = 0;
        for (; u + 4 <= nst; u += 4) {
            int j0 = u * 4 + g;
            int s0 = lds_s[wid][j0];       float x0 = lds_e[wid][j0];
            int s1 = lds_s[wid][j0 + 4];   float x1 = lds_e[wid][j0 + 4];
            int s2 = lds_s[wid][j0 + 8];   float x2 = lds_e[wid][j0 + 8];
            int s3 = lds_s[wid][j0 + 12];  float x3 = lds_e[wid][j0 + 12];
            uint4 h0 = *(const uint4*)&hb[(size_t)s0 * 128 + p * 8];
            uint4 h1 = *(const uint4*)&hb[(size_t)s1 * 128 + p * 8];
            uint4 h2 = *(const uint4*)&hb[(size_t)s2 * 128 + p * 8];
            uint4 h3 = *(const uint4*)&hb[(size_t)s3 * 128 + p * 8];
#define ACC8(hv, xe)                                                        \
            acc[0] += xe * __uint_as_float(hv.x << 16);                     \
            acc[1] += xe * __uint_as_float(hv.x & 0xffff0000u);             \
            acc[2] += xe * __uint_as_float(hv.y << 16);                     \
            acc[3] += xe * __uint_as_float(hv.y & 0xffff0000u);             \
            acc[4] += xe * __uint_as_float(hv.z << 16);                     \
            acc[5] += xe * __uint_as_float(hv.z & 0xffff0000u);             \
            acc[6] += xe * __uint_as_float(hv.w << 16);                     \
            acc[7] += xe * __uint_as_float(hv.w & 0xffff0000u);
            ACC8(h0, x0) ACC8(h1, x1) ACC8(h2, x2) ACC8(h3, x3)
        }
        for (; u < nst; ++u) {
            int j = u * 4 + g;
            int sj = lds_s[wid][j];
            float xj = lds_e[wid][j];
            uint4 hv = *(const uint4*)&hb[(size_t)sj * 128 + p * 8];
            ACC8(hv, xj)
        }
#undef ACC8
    }

    // cross-group reduce (columns live in lanes p, p+16, p+32, p+48)
#pragma unroll
    for (int q = 0; q < 8; ++q) {
        acc[q] += __shfl_xor(acc[q], 16);
        acc[q] += __shfl_xor(acc[q], 32);
    }
#pragma unroll
    for (int o = 32; o; o >>= 1) denom += __shfl_xor(denom, o);
    float inv = 1.f / fmaxf(denom, 1e-38f);

    if (g == 0) {
        float4 o0 = make_float4(acc[0] * inv, acc[1] * inv, acc[2] * inv, acc[3] * inv);
        float4 o1 = make_float4(acc[4] * inv, acc[5] * inv, acc[6] * inv, acc[7] * inv);
        *(float4*)&out[(size_t)d * 128 + p * 8] = o0;
        *(float4*)&out[(size_t)d * 128 + p * 8 + 4] = o1;
    }
}

extern "C" void kernel_launch(void* const* d_in, const int* in_sizes, int n_in,
                              void* d_out, int out_size, void* d_ws, size_t ws_size,
                              hipStream_t stream) {
    const float* x   = (const float*)d_in[0];
    const int*   src = (const int*)d_in[1];
    const int*   dst = (const int*)d_in[2];
    const float* W   = (const float*)d_in[3];
    const float* a_l = (const float*)d_in[4];
    const float* a_r = (const float*)d_in[5];
    float* out = (float*)d_out;

    char* ws = (char*)d_ws;
    unsigned short* hb = (unsigned short*)ws; ws += (size_t)N_NODES * D * 2;
    float* e_l       = (float*)ws; ws += (size_t)N_NODES * 4;
    float* e_r       = (float*)ws; ws += (size_t)N_NODES * 4;
    int*   deg       = (int*)ws;   ws += (size_t)N_NODES * 4;
    int*   row_ptr   = (int*)ws;   ws += (size_t)(N_NODES + 1) * 4;
    int*   cursor    = (int*)ws;   ws += (size_t)N_NODES * 4;
    int*   src_sorted= (int*)ws;   ws += (size_t)N_EDGES * 4;
    int*   bsum      = (int*)ws;   ws += (size_t)NSB * 4;
    int*   bofs      = (int*)ws;   ws += (size_t)NSB * 4;

    hipMemsetAsync(deg, 0, (size_t)N_NODES * 4, stream);

    gemm_h<<<(N_NODES + 63) / 64, 256, 0, stream>>>(x, W, a_l, a_r, hb, e_l, e_r, N_NODES);
    hist<<<(N_EDGES + 255) / 256, 256, 0, stream>>>(dst, deg);
    block_sums<<<NSB, 256, 0, stream>>>(deg, bsum);
    scan_bsums<<<1, 128, 0, stream>>>(bsum, bofs, row_ptr);
    emit_rowptr<<<NSB, 256, 0, stream>>>(deg, bofs, row_ptr, cursor);
    scatter<<<(N_EDGES + 255) / 256, 256, 0, stream>>>(src, dst, cursor, src_sorted);
    node_aggregate<<<(N_NODES + 3) / 4, 256, 0, stream>>>(hb, e_l, e_r, row_ptr, src_sorted, out);
}

// Round 4
// 282.407 us; speedup vs baseline: 2.3214x; 1.1914x over previous
//
#include <hip/hip_runtime.h>
#include <math.h>

#define N_NODES 100000
#define N_EDGES 1600000
#define D 128
#define NEG_SLOPE_F 0.2f
#define NSB 98   // ceil(N_NODES / 1024) scan blocks
#define NBUK 196 // ceil(N_NODES / 512) dst buckets
#define EPT 16   // edges per thread in bin_edges
#define EPB 4096 // edges per block in bin_edges (256 * 16)

__device__ __forceinline__ unsigned short f2bf_rtn(float f) {
    unsigned int u = __float_as_uint(f);
    u += 0x7fffu + ((u >> 16) & 1u);  // round-to-nearest-even
    return (unsigned short)(u >> 16);
}

// ---------------- GEMM: h = x @ W^T (bf16 out), fused e_l/e_r epilogue --------
// Two K-phases of 64 so LDS = 52 KB -> 3 blocks/CU.
__global__ __launch_bounds__(256) void gemm_h(const float* __restrict__ x,
                                              const float* __restrict__ W,
                                              const float* __restrict__ a_l,
                                              const float* __restrict__ a_r,
                                              unsigned short* __restrict__ hb,
                                              float* __restrict__ e_l,
                                              float* __restrict__ e_r, int n) {
    __shared__ float Xs[64][68];
    __shared__ float Ws[128][68];
    int tid = threadIdx.x;
    int tx = tid & 15, ty = tid >> 4;
    int row0 = blockIdx.x * 64;

    float acc[4][8];
#pragma unroll
    for (int i = 0; i < 4; ++i)
#pragma unroll
        for (int j = 0; j < 8; ++j) acc[i][j] = 0.f;

    const float4* W4 = (const float4*)W;
    const float4* X4 = (const float4*)x;

    for (int ph = 0; ph < 2; ++ph) {
        for (int i = 0; i < 8; ++i) {
            int idx = tid + i * 256;
            int r = idx >> 4;
            int c4 = idx & 15;
            float4 v = W4[r * 32 + ph * 16 + c4];
            *(float4*)&Ws[r][c4 * 4] = v;
        }
        for (int i = 0; i < 4; ++i) {
            int idx = tid + i * 256;
            int r = idx >> 4;
            int c4 = idx & 15;
            int gr = row0 + r;
            float4 v = (gr < n) ? X4[(size_t)gr * 32 + ph * 16 + c4]
                                : make_float4(0.f, 0.f, 0.f, 0.f);
            *(float4*)&Xs[r][c4 * 4] = v;
        }
        __syncthreads();

        for (int k4 = 0; k4 < 16; ++k4) {
            float4 xf[4], wf[8];
#pragma unroll
            for (int i = 0; i < 4; ++i) xf[i] = *(const float4*)&Xs[ty + 16 * i][k4 * 4];
#pragma unroll
            for (int j = 0; j < 8; ++j) wf[j] = *(const float4*)&Ws[tx + 16 * j][k4 * 4];
#pragma unroll
            for (int i = 0; i < 4; ++i)
#pragma unroll
                for (int j = 0; j < 8; ++j) {
                    acc[i][j] += xf[i].x * wf[j].x + xf[i].y * wf[j].y +
                                 xf[i].z * wf[j].z + xf[i].w * wf[j].w;
                }
        }
        __syncthreads();
    }

    // write h (bf16)
#pragma unroll
    for (int i = 0; i < 4; ++i) {
        int gr = row0 + ty + 16 * i;
        if (gr < n) {
#pragma unroll
            for (int j = 0; j < 8; ++j)
                hb[(size_t)gr * 128 + tx + 16 * j] = f2bf_rtn(acc[i][j]);
        }
    }

    // fused epilogue: e_l[r] = h[r]·a_l, e_r[r] = h[r]·a_r (fp32 acc)
    float pl[4] = {0.f, 0.f, 0.f, 0.f}, pr[4] = {0.f, 0.f, 0.f, 0.f};
#pragma unroll
    for (int j = 0; j < 8; ++j) {
        float alv = a_l[tx + 16 * j];
        float arv = a_r[tx + 16 * j];
#pragma unroll
        for (int i = 0; i < 4; ++i) {
            pl[i] += acc[i][j] * alv;
            pr[i] += acc[i][j] * arv;
        }
    }
#pragma unroll
    for (int o = 8; o; o >>= 1) {
#pragma unroll
        for (int i = 0; i < 4; ++i) {
            pl[i] += __shfl_xor(pl[i], o);
            pr[i] += __shfl_xor(pr[i], o);
        }
    }
    if (tx == 0) {
#pragma unroll
        for (int i = 0; i < 4; ++i) {
            int gr = row0 + ty + 16 * i;
            if (gr < n) { e_l[gr] = pl[i]; e_r[gr] = pr[i]; }
        }
    }
}

// ---------------- degree histogram ----------------
__global__ void hist(const int* __restrict__ dst, int* __restrict__ deg) {
    int i = blockIdx.x * blockDim.x + threadIdx.x;
    if (i < N_EDGES) atomicAdd(&deg[dst[i]], 1);
}

// ---------------- parallel scan, 3 kernels ----------------
__global__ __launch_bounds__(256) void block_sums(const int* __restrict__ deg,
                                                  int* __restrict__ bsum) {
    int tid = threadIdx.x, lane = tid & 63, wid = tid >> 6;
    int base = blockIdx.x * 1024 + tid * 4;
    int s = 0;
#pragma unroll
    for (int k = 0; k < 4; ++k) {
        int i = base + k;
        if (i < N_NODES) s += deg[i];
    }
#pragma unroll
    for (int o = 32; o; o >>= 1) s += __shfl_xor(s, o);
    __shared__ int wt[4];
    if (lane == 0) wt[wid] = s;
    __syncthreads();
    if (tid == 0) bsum[blockIdx.x] = wt[0] + wt[1] + wt[2] + wt[3];
}

__global__ __launch_bounds__(128) void scan_bsums(const int* __restrict__ bsum,
                                                  int* __restrict__ bofs,
                                                  int* __restrict__ row_ptr) {
    int tid = threadIdx.x, lane = tid & 63, wid = tid >> 6;
    int v = (tid < NSB) ? bsum[tid] : 0;
    int inc = v;
#pragma unroll
    for (int o = 1; o < 64; o <<= 1) {
        int nv = __shfl_up(inc, o);
        if (lane >= o) inc += nv;
    }
    __shared__ int wtot[2];
    if (lane == 63) wtot[wid] = inc;
    __syncthreads();
    int add = (wid == 1) ? wtot[0] : 0;
    int excl = inc - v + add;
    if (tid < NSB) bofs[tid] = excl;
    if (tid == NSB - 1) row_ptr[N_NODES] = excl + v;
}

__global__ __launch_bounds__(256) void emit_rowptr(const int* __restrict__ deg,
                                                   const int* __restrict__ bofs,
                                                   int* __restrict__ row_ptr,
                                                   int* __restrict__ cursor) {
    int tid = threadIdx.x, lane = tid & 63, wid = tid >> 6;
    int base = blockIdx.x * 1024 + tid * 4;
    int v[4];
    int s = 0;
#pragma unroll
    for (int k = 0; k < 4; ++k) {
        int i = base + k;
        v[k] = (i < N_NODES) ? deg[i] : 0;
        s += v[k];
    }
    int inc = s;
#pragma unroll
    for (int o = 1; o < 64; o <<= 1) {
        int nv = __shfl_up(inc, o);
        if (lane >= o) inc += nv;
    }
    __shared__ int wt[4];
    if (lane == 63) wt[wid] = inc;
    __syncthreads();
    int wofs = 0;
#pragma unroll
    for (int w = 0; w < 4; ++w)
        if (w < wid) wofs += wt[w];
    int excl = inc - s + wofs + bofs[blockIdx.x];
#pragma unroll
    for (int k = 0; k < 4; ++k) {
        int i = base + k;
        if (i < N_NODES) { row_ptr[i] = excl; cursor[i] = excl; }
        excl += v[k];
    }
}

// ---------------- bucket cursor init: binned region starts = CSR starts -------
__global__ void init_bcur(const int* __restrict__ row_ptr, int* __restrict__ bcur) {
    int b = blockIdx.x * blockDim.x + threadIdx.x;
    if (b < NBUK) bcur[b] = row_ptr[min(b * 512, N_NODES)];
}

// ---------------- coarse bin by dst>>9 (196 buckets of 512 nodes) -------------
// Per-block LDS hist -> one global reservation per (block,bucket) -> packed
// uint2 writes contiguous within each reservation.
__global__ __launch_bounds__(256) void bin_edges(const int* __restrict__ src,
                                                 const int* __restrict__ dst,
                                                 int* __restrict__ bcur,
                                                 uint2* __restrict__ binned) {
    __shared__ int histb[NBUK];
    __shared__ int startb[NBUK];
    __shared__ int cnt2[NBUK];
    int tid = threadIdx.x;
    for (int i = tid; i < NBUK; i += 256) { histb[i] = 0; cnt2[i] = 0; }
    __syncthreads();

    int base = blockIdx.x * EPB + tid;
    int s[EPT], dd[EPT];
#pragma unroll
    for (int k = 0; k < EPT; ++k) {
        int i = base + k * 256;
        if (i < N_EDGES) {
            s[k] = src[i];
            dd[k] = dst[i];
            atomicAdd(&histb[dd[k] >> 9], 1);
        } else {
            dd[k] = -1;
        }
    }
    __syncthreads();
    for (int b = tid; b < NBUK; b += 256) {
        int c = histb[b];
        startb[b] = c ? atomicAdd(&bcur[b], c) : 0;
    }
    __syncthreads();
#pragma unroll
    for (int k = 0; k < EPT; ++k) {
        if (dd[k] >= 0) {
            int b = dd[k] >> 9;
            int lr = atomicAdd(&cnt2[b], 1);
            binned[startb[b] + lr] = make_uint2((unsigned)s[k], (unsigned)dd[k]);
        }
    }
}

// ---------------- fine scatter from binned stream (write-local) --------------
__global__ void scatter2(const uint2* __restrict__ binned,
                         int* __restrict__ cursor, int* __restrict__ src_sorted) {
    int i = blockIdx.x * blockDim.x + threadIdx.x;
    if (i < N_EDGES) {
        uint2 e = binned[i];
        int p = atomicAdd(&cursor[e.y], 1);
        src_sorted[p] = (int)e.x;
    }
}

// ---------------- per-node softmax + aggregation ----------------
__global__ __launch_bounds__(256) void node_aggregate(
        const unsigned short* __restrict__ hb, const float* __restrict__ e_l,
        const float* __restrict__ e_r, const int* __restrict__ row_ptr,
        const int* __restrict__ src_sorted, float* __restrict__ out) {
    __shared__ int   lds_s[4][64];
    __shared__ float lds_e[4][64];
    int wid = threadIdx.x >> 6, lane = threadIdx.x & 63;
    int g = lane >> 4, p = lane & 15;
    int d = blockIdx.x * 4 + wid;
    if (d >= N_NODES) return;
    int start = row_ptr[d], end = row_ptr[d + 1];
    float erd = e_r[d];

    // pass 1: segment max of leaky-relu logits
    float m = -INFINITY;
    for (int base = start; base < end; base += 64) {
        int k = base + lane;
        if (k < end) {
            float e = e_l[src_sorted[k]] + erd;
            e = (e >= 0.f) ? e : NEG_SLOPE_F * e;
            m = fmaxf(m, e);
        }
    }
#pragma unroll
    for (int o = 32; o; o >>= 1) m = fmaxf(m, __shfl_xor(m, o));

    // pass 2: exp + weighted accumulation
    float denom = 0.f;
    float acc[8];
#pragma unroll
    for (int q = 0; q < 8; ++q) acc[q] = 0.f;

    for (int base = start; base < end; base += 64) {
        int k = base + lane;
        int valid = k < end;
        int s = valid ? src_sorted[k] : 0;
        float ex = 0.f;
        if (valid) {
            float e = e_l[s] + erd;
            e = (e >= 0.f) ? e : NEG_SLOPE_F * e;
            ex = __expf(e - m);
        }
        denom += ex;
        lds_s[wid][lane] = s;
        lds_e[wid][lane] = ex;
        asm volatile("s_waitcnt lgkmcnt(0)" ::: "memory");

        int cnt = min(64, end - base);
        int nst = (cnt + 3) >> 2;
        int u = 0;
        for (; u + 4 <= nst; u += 4) {
            int j0 = u * 4 + g;
            int s0 = lds_s[wid][j0];       float x0 = lds_e[wid][j0];
            int s1 = lds_s[wid][j0 + 4];   float x1 = lds_e[wid][j0 + 4];
            int s2 = lds_s[wid][j0 + 8];   float x2 = lds_e[wid][j0 + 8];
            int s3 = lds_s[wid][j0 + 12];  float x3 = lds_e[wid][j0 + 12];
            uint4 h0 = *(const uint4*)&hb[(size_t)s0 * 128 + p * 8];
            uint4 h1 = *(const uint4*)&hb[(size_t)s1 * 128 + p * 8];
            uint4 h2 = *(const uint4*)&hb[(size_t)s2 * 128 + p * 8];
            uint4 h3 = *(const uint4*)&hb[(size_t)s3 * 128 + p * 8];
#define ACC8(hv, xe)                                                        \
            acc[0] += xe * __uint_as_float(hv.x << 16);                     \
            acc[1] += xe * __uint_as_float(hv.x & 0xffff0000u);             \
            acc[2] += xe * __uint_as_float(hv.y << 16);                     \
            acc[3] += xe * __uint_as_float(hv.y & 0xffff0000u);             \
            acc[4] += xe * __uint_as_float(hv.z << 16);                     \
            acc[5] += xe * __uint_as_float(hv.z & 0xffff0000u);             \
            acc[6] += xe * __uint_as_float(hv.w << 16);                     \
            acc[7] += xe * __uint_as_float(hv.w & 0xffff0000u);
            ACC8(h0, x0) ACC8(h1, x1) ACC8(h2, x2) ACC8(h3, x3)
        }
        for (; u < nst; ++u) {
            int j = u * 4 + g;
            int sj = lds_s[wid][j];
            float xj = lds_e[wid][j];
            uint4 hv = *(const uint4*)&hb[(size_t)sj * 128 + p * 8];
            ACC8(hv, xj)
        }
#undef ACC8
    }

    // cross-group reduce (columns live in lanes p, p+16, p+32, p+48)
#pragma unroll
    for (int q = 0; q < 8; ++q) {
        acc[q] += __shfl_xor(acc[q], 16);
        acc[q] += __shfl_xor(acc[q], 32);
    }
#pragma unroll
    for (int o = 32; o; o >>= 1) denom += __shfl_xor(denom, o);
    float inv = 1.f / fmaxf(denom, 1e-38f);

    if (g == 0) {
        float4 o0 = make_float4(acc[0] * inv, acc[1] * inv, acc[2] * inv, acc[3] * inv);
        float4 o1 = make_float4(acc[4] * inv, acc[5] * inv, acc[6] * inv, acc[7] * inv);
        *(float4*)&out[(size_t)d * 128 + p * 8] = o0;
        *(float4*)&out[(size_t)d * 128 + p * 8 + 4] = o1;
    }
}

extern "C" void kernel_launch(void* const* d_in, const int* in_sizes, int n_in,
                              void* d_out, int out_size, void* d_ws, size_t ws_size,
                              hipStream_t stream) {
    const float* x   = (const float*)d_in[0];
    const int*   src = (const int*)d_in[1];
    const int*   dst = (const int*)d_in[2];
    const float* W   = (const float*)d_in[3];
    const float* a_l = (const float*)d_in[4];
    const float* a_r = (const float*)d_in[5];
    float* out = (float*)d_out;

    char* ws = (char*)d_ws;
    unsigned short* hb = (unsigned short*)ws; ws += (size_t)N_NODES * D * 2;
    float* e_l       = (float*)ws; ws += (size_t)N_NODES * 4;
    float* e_r       = (float*)ws; ws += (size_t)N_NODES * 4;
    int*   deg       = (int*)ws;   ws += (size_t)N_NODES * 4;
    int*   row_ptr   = (int*)ws;   ws += (size_t)(N_NODES + 1) * 4;
    int*   cursor    = (int*)ws;   ws += (size_t)N_NODES * 4;
    int*   src_sorted= (int*)ws;   ws += (size_t)N_EDGES * 4;
    uint2* binned    = (uint2*)ws; ws += (size_t)N_EDGES * 8;
    int*   bsum      = (int*)ws;   ws += (size_t)NSB * 4;
    int*   bofs      = (int*)ws;   ws += (size_t)NSB * 4;
    int*   bcur      = (int*)ws;   ws += (size_t)NBUK * 4;

    hipMemsetAsync(deg, 0, (size_t)N_NODES * 4, stream);

    gemm_h<<<(N_NODES + 63) / 64, 256, 0, stream>>>(x, W, a_l, a_r, hb, e_l, e_r, N_NODES);
    hist<<<(N_EDGES + 255) / 256, 256, 0, stream>>>(dst, deg);
    block_sums<<<NSB, 256, 0, stream>>>(deg, bsum);
    scan_bsums<<<1, 128, 0, stream>>>(bsum, bofs, row_ptr);
    emit_rowptr<<<NSB, 256, 0, stream>>>(deg, bofs, row_ptr, cursor);
    init_bcur<<<1, 256, 0, stream>>>(row_ptr, bcur);
    bin_edges<<<(N_EDGES + EPB - 1) / EPB, 256, 0, stream>>>(src, dst, bcur, binned);
    scatter2<<<(N_EDGES + 255) / 256, 256, 0, stream>>>(binned, cursor, src_sorted);
    node_aggregate<<<(N_NODES + 3) / 4, 256, 0, stream>>>(hb, e_l, e_r, row_ptr, src_sorted, out);
}